// Round 1
// baseline (1997.815 us; speedup 1.0000x reference)
//
#include <hip/hip_runtime.h>
#include <hip/hip_bf16.h>
#include <math.h>

#define E_CNT 600000
#define N_CNT 50000
#define H_DIM 128
#define OE_DIM 256
#define NPB 64
#define NTHREADS 512

// ---------------------------------------------------------------------------
// Edge stage: xe[e,h] = (sum_k rbf[e,k]*W_rbf[h,k]) * x[e,h]; atomic scatter
// into xn[i[e], h]. Thread = (edge, 4-wide h quad); hq fixed per thread so the
// 24 W_rbf coefficients live in registers across the grid-stride loop.
// ---------------------------------------------------------------------------
__global__ __launch_bounds__(256) void edge_scatter_kernel(
    const float* __restrict__ x, const float* __restrict__ rbf,
    const int* __restrict__ nid, const float* __restrict__ W_rbf,
    float* __restrict__ xn)
{
    const int tid = threadIdx.x;
    const int hq = tid & 31;        // which h-quad (fixed per thread)
    const int h0 = hq << 2;

    float wr[4][6];
#pragma unroll
    for (int j = 0; j < 4; ++j)
#pragma unroll
        for (int k = 0; k < 6; ++k)
            wr[j][k] = W_rbf[(h0 + j) * 6 + k];

    int e = blockIdx.x * 8 + (tid >> 5);
    const int estride = gridDim.x * 8;
    for (; e < E_CNT; e += estride) {
        float r[6];
#pragma unroll
        for (int k = 0; k < 6; ++k) r[k] = rbf[e * 6 + k];
        const int node = nid[e];
        const float4 xv = *reinterpret_cast<const float4*>(x + (size_t)e * H_DIM + h0);
        float c0 = 0.f, c1 = 0.f, c2 = 0.f, c3 = 0.f;
#pragma unroll
        for (int k = 0; k < 6; ++k) {
            c0 = fmaf(r[k], wr[0][k], c0);
            c1 = fmaf(r[k], wr[1][k], c1);
            c2 = fmaf(r[k], wr[2][k], c2);
            c3 = fmaf(r[k], wr[3][k], c3);
        }
        float* dst = xn + (size_t)node * H_DIM + h0;
        atomicAdd(dst + 0, c0 * xv.x);
        atomicAdd(dst + 1, c1 * xv.y);
        atomicAdd(dst + 2, c2 * xv.z);
        atomicAdd(dst + 3, c3 * xv.w);
    }
}

// ---------------------------------------------------------------------------
// One dense layer: out[n][o] = act( sum_k in[n][k] * W[o][k] + b[o] )
// 512 threads, 64 nodes/block. Thread owns 4 outputs x 8 nodes.
// Within a wave all 64 lanes share the same node-group -> LDS reads are
// same-address broadcasts (conflict-free). Weight loads stream from L1/L2.
// ---------------------------------------------------------------------------
template<int K, bool SWISH>
__device__ __forceinline__ void dense_layer(
    const float* __restrict__ W, const float* __restrict__ bias,
    const float* in_s, float* out_s, int tid)
{
    const int og = tid & 63;
    const int ng = tid >> 6;
    const int o0 = og << 2;   // 4 outputs per thread
    const int n0 = ng << 3;   // 8 nodes per thread

    float acc[4][8];
#pragma unroll
    for (int j = 0; j < 4; ++j)
#pragma unroll
        for (int t = 0; t < 8; ++t) acc[j][t] = 0.f;

    for (int k = 0; k < K; k += 4) {
        float4 wv[4];
        float4 iv[8];
#pragma unroll
        for (int j = 0; j < 4; ++j)
            wv[j] = *reinterpret_cast<const float4*>(W + (o0 + j) * K + k);
#pragma unroll
        for (int t = 0; t < 8; ++t)
            iv[t] = *reinterpret_cast<const float4*>(in_s + (n0 + t) * K + k);
#pragma unroll
        for (int j = 0; j < 4; ++j)
#pragma unroll
            for (int t = 0; t < 8; ++t)
                acc[j][t] = fmaf(wv[j].x, iv[t].x,
                           fmaf(wv[j].y, iv[t].y,
                           fmaf(wv[j].z, iv[t].z,
                           fmaf(wv[j].w, iv[t].w, acc[j][t]))));
    }

    float bj[4];
#pragma unroll
    for (int j = 0; j < 4; ++j) bj[j] = bias[o0 + j];

#pragma unroll
    for (int t = 0; t < 8; ++t) {
        float vv[4];
#pragma unroll
        for (int j = 0; j < 4; ++j) {
            float v = acc[j][t] + bj[j];
            if (SWISH) v = v / (1.f + __expf(-v));
            vv[j] = v;
        }
        float4 ov;
        ov.x = vv[0]; ov.y = vv[1]; ov.z = vv[2]; ov.w = vv[3];
        *reinterpret_cast<float4*>(out_s + (n0 + t) * OE_DIM + o0) = ov;
    }
}

// ---------------------------------------------------------------------------
// Fused node pipeline: load xn tile -> alpha -> up(128->256) -> 3x swish
// layers (256->256) -> out dot * alpha. Activations ping-pong in LDS; the
// input tile aliases the front half of s_b (dead after the up layer).
// ---------------------------------------------------------------------------
__global__ __launch_bounds__(NTHREADS) void node_mlp_kernel(
    const float* __restrict__ xn,
    const float* __restrict__ W_up, const float* __restrict__ b_up,
    const float* __restrict__ W_l1, const float* __restrict__ b_l1,
    const float* __restrict__ W_l2, const float* __restrict__ b_l2,
    const float* __restrict__ W_l3, const float* __restrict__ b_l3,
    const float* __restrict__ W_out, const float* __restrict__ W_w,
    const float* __restrict__ b_w,
    float* __restrict__ out)
{
    __shared__ float s_a[NPB * OE_DIM];     // 64 KB
    __shared__ float s_b[NPB * OE_DIM];     // 64 KB (front 32KB doubles as input tile)
    __shared__ float s_alpha[NPB];

    const int tid = threadIdx.x;
    const int node0 = blockIdx.x * NPB;
    const int nvalid = min(NPB, N_CNT - node0);

    // Load xn tile [NPB][H] into s_b (flat contiguous), zero-padding the tail.
#pragma unroll
    for (int q = 0; q < 4; ++q) {
        int li = q * NTHREADS + tid;        // float4 index in [0, 2048)
        int n = li >> 5;                    // 32 float4 per node row
        float4 v = make_float4(0.f, 0.f, 0.f, 0.f);
        if (n < nvalid)
            v = *reinterpret_cast<const float4*>(
                    xn + (size_t)(node0 + n) * H_DIM + ((li & 31) << 2));
        *reinterpret_cast<float4*>(s_b + (size_t)li * 4) = v;
    }
    __syncthreads();

    // alpha[n] = xn[n,:] . W_w + b_w   (8 threads per node)
    {
        const int n = tid >> 3, s = tid & 7;
        float part = 0.f;
#pragma unroll
        for (int h = 0; h < 16; ++h) {
            int hh = s * 16 + h;
            part = fmaf(s_b[n * H_DIM + hh], W_w[hh], part);
        }
        part += __shfl_xor(part, 1);
        part += __shfl_xor(part, 2);
        part += __shfl_xor(part, 4);
        if (s == 0) s_alpha[n] = part + b_w[0];
    }

    dense_layer<H_DIM, false>(W_up, b_up, s_b, s_a, tid);
    __syncthreads();
    dense_layer<OE_DIM, true>(W_l1, b_l1, s_a, s_b, tid);
    __syncthreads();
    dense_layer<OE_DIM, true>(W_l2, b_l2, s_b, s_a, tid);
    __syncthreads();
    dense_layer<OE_DIM, true>(W_l3, b_l3, s_a, s_b, tid);
    __syncthreads();

    // out[n] = (x2[n,:] . W_out) * alpha[n]   (8 threads per node)
    {
        const int n = tid >> 3, s = tid & 7;
        float part = 0.f;
#pragma unroll
        for (int o = 0; o < 32; ++o) {
            int oo = s * 32 + o;
            part = fmaf(s_b[n * OE_DIM + oo], W_out[oo], part);
        }
        part += __shfl_xor(part, 1);
        part += __shfl_xor(part, 2);
        part += __shfl_xor(part, 4);
        if (s == 0 && n < nvalid) out[node0 + n] = part * s_alpha[n];
    }
}

__global__ __launch_bounds__(256) void batch_out_kernel(
    const int* __restrict__ batch, float* __restrict__ out)
{
    int n = blockIdx.x * 256 + threadIdx.x;
    if (n < N_CNT) out[N_CNT + n] = (float)batch[n];
}

extern "C" void kernel_launch(void* const* d_in, const int* in_sizes, int n_in,
                              void* d_out, int out_size, void* d_ws, size_t ws_size,
                              hipStream_t stream)
{
    const float* x      = (const float*)d_in[0];
    const float* rbf    = (const float*)d_in[1];
    const int*   nid    = (const int*)d_in[2];
    // d_in[3] edge_index, d_in[4] edge_weight, d_in[6] num_nodes: unused
    const int*   batch  = (const int*)d_in[5];
    const float* W_rbf  = (const float*)d_in[7];
    const float* W_up   = (const float*)d_in[8];
    const float* b_up   = (const float*)d_in[9];
    const float* W_l1   = (const float*)d_in[10];
    const float* b_l1   = (const float*)d_in[11];
    const float* W_l2   = (const float*)d_in[12];
    const float* b_l2   = (const float*)d_in[13];
    const float* W_l3   = (const float*)d_in[14];
    const float* b_l3   = (const float*)d_in[15];
    const float* W_out  = (const float*)d_in[16];
    const float* W_w    = (const float*)d_in[17];
    const float* b_w    = (const float*)d_in[18];

    float* xn  = (float*)d_ws;               // N*H floats = 25.6 MB scratch
    float* out = (float*)d_out;              // [0,N): result, [N,2N): batch

    hipMemsetAsync(xn, 0, (size_t)N_CNT * H_DIM * sizeof(float), stream);
    edge_scatter_kernel<<<2048, 256, 0, stream>>>(x, rbf, nid, W_rbf, xn);
    node_mlp_kernel<<<(N_CNT + NPB - 1) / NPB, NTHREADS, 0, stream>>>(
        xn, W_up, b_up, W_l1, b_l1, W_l2, b_l2, W_l3, b_l3, W_out, W_w, b_w, out);
    batch_out_kernel<<<(N_CNT + 255) / 256, 256, 0, stream>>>(batch, out);
}

// Round 2
// 375.378 us; speedup vs baseline: 5.3221x; 5.3221x over previous
//
#include <hip/hip_runtime.h>
#include <hip/hip_bf16.h>
#include <math.h>

#define E_CNT 600000
#define N_CNT 50000
#define H_DIM 128
#define OE_DIM 256

typedef __attribute__((ext_vector_type(8))) short short8;
typedef __attribute__((ext_vector_type(4))) float f32x4;

// ---------------- workspace layout (bytes) — total ~16.8 MB (<25.6 MB known-safe)
#define WS_EIDS   0            // int[E]            2,400,000
#define WS_OFF    2400000      // int[N+1]            200,004
#define WS_CURS   2600008      // int[N]              200,000
#define WS_CNT    2800008      // int[N]              200,000
#define WS_ALPHA  3000008      // float[N]            200,000
#define WS_WUP    3200016      // ushort[32768]        65,536
#define WS_WL1    3265552      // ushort[65536]       131,072
#define WS_WL2    3396624      // ushort[65536]       131,072
#define WS_WL3    3527696      // ushort[65536]       131,072
#define WS_XN     4000000      // ushort[N*128]    12,800,000

// ---------------------------------------------------------------------------
// CSR build: histogram -> single-block scan -> fill
// ---------------------------------------------------------------------------
__global__ __launch_bounds__(256) void hist_kernel(const int* __restrict__ nid,
                                                   int* __restrict__ counts)
{
    for (int e = blockIdx.x * 256 + threadIdx.x; e < E_CNT; e += gridDim.x * 256)
        atomicAdd(&counts[nid[e]], 1);
}

__global__ __launch_bounds__(1024) void scan_kernel(const int* __restrict__ counts,
                                                    int* __restrict__ offs,
                                                    int* __restrict__ cursor)
{
    __shared__ int s[1024];
    const int t = threadIdx.x;
    const int CH = 49;                       // 1024*49 = 50176 >= N
    const int base = t * CH;
    int sum = 0;
    for (int i = 0; i < CH; ++i) {
        int idx = base + i;
        if (idx < N_CNT) sum += counts[idx];
    }
    s[t] = sum;
    __syncthreads();
    for (int off = 1; off < 1024; off <<= 1) {
        int v = (t >= off) ? s[t - off] : 0;
        __syncthreads();
        s[t] += v;
        __syncthreads();
    }
    int run = s[t] - sum;                    // exclusive prefix
    for (int i = 0; i < CH; ++i) {
        int idx = base + i;
        if (idx < N_CNT) {
            offs[idx] = run;
            cursor[idx] = run;
            run += counts[idx];
        }
    }
    if (t == 1023) offs[N_CNT] = E_CNT;
}

__global__ __launch_bounds__(256) void fill_kernel(const int* __restrict__ nid,
                                                   int* __restrict__ cursor,
                                                   int* __restrict__ eids)
{
    for (int e = blockIdx.x * 256 + threadIdx.x; e < E_CNT; e += gridDim.x * 256) {
        int slot = atomicAdd(&cursor[nid[e]], 1);
        eids[slot] = e;
    }
}

// ---------------------------------------------------------------------------
// Weight shuffle: f32 [O][K] -> bf16 in exact MFMA b-frag order so the MLP
// loads are 1KB-coalesced: dst[((ot*KS+ks)*64 + lane)*8 + j]
//   = W[ot*16 + (lane&15)][ks*32 + 8*(lane>>4) + j]
// ---------------------------------------------------------------------------
__global__ __launch_bounds__(256) void wconv_kernel(const float* __restrict__ W,
                                                    ushort* __restrict__ dst,
                                                    int K, int total)
{
    int d = blockIdx.x * 256 + threadIdx.x;
    if (d >= total) return;
    int j = d & 7;
    int l = (d >> 3) & 63;
    int KS = K >> 5;
    int ks = (d >> 9) % KS;
    int ot = (d >> 9) / KS;
    int k = ks * 32 + ((l >> 4) << 3) + j;
    int o = ot * 16 + (l & 15);
    __hip_bfloat16 h = __float2bfloat16(W[o * K + k]);
    dst[d] = *(const ushort*)&h;
}

// ---------------------------------------------------------------------------
// Gather: one wave per node. Lane owns 2 h's. Sums (rbf.Wrbf_h)*x_h over the
// node's CSR edge list (unrolled x2 for load overlap), writes xn row as bf16,
// computes alpha = xn . W_w + b_w in f32 via wave reduction.
// ---------------------------------------------------------------------------
__global__ __launch_bounds__(256) void gather_kernel(
    const float* __restrict__ x, const float* __restrict__ rbf,
    const int* __restrict__ offs, const int* __restrict__ eids,
    const float* __restrict__ W_rbf, const float* __restrict__ W_w,
    const float* __restrict__ b_w,
    ushort* __restrict__ xn16, float* __restrict__ alpha)
{
    const int lane = threadIdx.x & 63;
    const int node = blockIdx.x * 4 + (threadIdx.x >> 6);   // grid covers N exactly
    const int h0 = lane * 2;

    float w0[6], w1[6];
#pragma unroll
    for (int k = 0; k < 6; ++k) {
        w0[k] = W_rbf[h0 * 6 + k];
        w1[k] = W_rbf[(h0 + 1) * 6 + k];
    }
    const float ww0 = W_w[h0], ww1 = W_w[h0 + 1];

    const int s = offs[node], e = offs[node + 1];
    float a0 = 0.f, a1 = 0.f;
    int i = s;
    for (; i + 1 < e; i += 2) {
        int e0 = eids[i], e1 = eids[i + 1];
        const float2 x0 = *(const float2*)(x + (size_t)e0 * H_DIM + h0);
        const float2 x1 = *(const float2*)(x + (size_t)e1 * H_DIM + h0);
        float r0[6], r1[6];
#pragma unroll
        for (int k = 0; k < 6; ++k) { r0[k] = rbf[e0 * 6 + k]; r1[k] = rbf[e1 * 6 + k]; }
        float s00 = 0.f, s01 = 0.f, s10 = 0.f, s11 = 0.f;
#pragma unroll
        for (int k = 0; k < 6; ++k) {
            s00 = fmaf(r0[k], w0[k], s00); s01 = fmaf(r0[k], w1[k], s01);
            s10 = fmaf(r1[k], w0[k], s10); s11 = fmaf(r1[k], w1[k], s11);
        }
        a0 = fmaf(s00, x0.x, fmaf(s10, x1.x, a0));
        a1 = fmaf(s01, x0.y, fmaf(s11, x1.y, a1));
    }
    if (i < e) {
        int e0 = eids[i];
        const float2 x0 = *(const float2*)(x + (size_t)e0 * H_DIM + h0);
        float r0[6];
#pragma unroll
        for (int k = 0; k < 6; ++k) r0[k] = rbf[e0 * 6 + k];
        float s00 = 0.f, s01 = 0.f;
#pragma unroll
        for (int k = 0; k < 6; ++k) {
            s00 = fmaf(r0[k], w0[k], s00); s01 = fmaf(r0[k], w1[k], s01);
        }
        a0 = fmaf(s00, x0.x, a0);
        a1 = fmaf(s01, x0.y, a1);
    }

    __hip_bfloat16 b0 = __float2bfloat16(a0), b1 = __float2bfloat16(a1);
    ushort2 pk;
    pk.x = *(const ushort*)&b0;
    pk.y = *(const ushort*)&b1;
    *(ushort2*)(xn16 + (size_t)node * H_DIM + h0) = pk;

    float part = fmaf(a0, ww0, a1 * ww1);
    part += __shfl_xor(part, 1);
    part += __shfl_xor(part, 2);
    part += __shfl_xor(part, 4);
    part += __shfl_xor(part, 8);
    part += __shfl_xor(part, 16);
    part += __shfl_xor(part, 32);
    if (lane == 0) alpha[node] = part + b_w[0];
}

// ---------------------------------------------------------------------------
// MFMA MLP. 64 nodes/block, 256 threads (4 waves). Wave w owns o-tiles
// [4w..4w+3], all 4 m-tiles. Activations ping-pong in LDS as bf16 with padded
// pitch (264 ush = 528 B) for near-conflict-free ds_read_b128.
// mfma_f32_16x16x32_bf16: a[lane l] = A[l&15][8*(l>>4)+j];
// D[lane l][r] = out[4*(l>>4)+r][l&15] (m89-verified mapping).
// ---------------------------------------------------------------------------
#define MB 64
#define PITCH 264

template<int KS, bool SW>
__device__ __forceinline__ void layer(const ushort* __restrict__ Wsh,
                                      const float* __restrict__ bias,
                                      const ushort* in_s, ushort* out_s, int tid)
{
    const int w = tid >> 6, lane = tid & 63;
    const int l15 = lane & 15, lg = lane >> 4;

    f32x4 acc[4][4];
#pragma unroll
    for (int mi = 0; mi < 4; ++mi)
#pragma unroll
        for (int oi = 0; oi < 4; ++oi)
            acc[mi][oi] = (f32x4){0.f, 0.f, 0.f, 0.f};

    for (int ks = 0; ks < KS; ++ks) {
        short8 b[4];
#pragma unroll
        for (int oi = 0; oi < 4; ++oi)
            b[oi] = *(const short8*)(Wsh + (size_t)(((w * 4 + oi) * KS + ks) * 64 + lane) * 8);
#pragma unroll
        for (int mi = 0; mi < 4; ++mi) {
            short8 a = *(const short8*)(in_s + (mi * 16 + l15) * PITCH + ks * 32 + lg * 8);
#pragma unroll
            for (int oi = 0; oi < 4; ++oi)
                acc[mi][oi] = __builtin_amdgcn_mfma_f32_16x16x32_bf16(a, b[oi], acc[mi][oi], 0, 0, 0);
        }
    }

#pragma unroll
    for (int oi = 0; oi < 4; ++oi) {
        float bv = bias[(w * 4 + oi) * 16 + l15];
#pragma unroll
        for (int mi = 0; mi < 4; ++mi)
#pragma unroll
            for (int r = 0; r < 4; ++r) {
                float v = acc[mi][oi][r] + bv;
                if (SW) v = v / (1.f + __expf(-v));
                __hip_bfloat16 h = __float2bfloat16(v);
                out_s[(mi * 16 + lg * 4 + r) * PITCH + (w * 4 + oi) * 16 + l15] =
                    *(const ushort*)&h;
            }
    }
}

__global__ __launch_bounds__(256) void mlp_kernel(
    const ushort* __restrict__ xn16,
    const ushort* __restrict__ Wup, const ushort* __restrict__ Wl1,
    const ushort* __restrict__ Wl2, const ushort* __restrict__ Wl3,
    const float* __restrict__ b_up, const float* __restrict__ b_l1,
    const float* __restrict__ b_l2, const float* __restrict__ b_l3,
    const float* __restrict__ W_out, const float* __restrict__ alpha,
    float* __restrict__ out)
{
    __shared__ ushort sA[MB * PITCH];
    __shared__ ushort sB[MB * PITCH];
    const int tid = threadIdx.x;
    const int node0 = blockIdx.x * MB;

    // stage xn tile (bf16, 256 B/row) into sA[:, 0:128]
    {
        int row = tid >> 2, seg = tid & 3;
        int node = node0 + row;
        ushort* dst = sA + row * PITCH + seg * 32;
        if (node < N_CNT) {
            const int4* src = (const int4*)(xn16 + (size_t)node * H_DIM + seg * 32);
#pragma unroll
            for (int u = 0; u < 4; ++u) *(int4*)(dst + u * 8) = src[u];
        } else {
#pragma unroll
            for (int u = 0; u < 4; ++u) *(int4*)(dst + u * 8) = make_int4(0, 0, 0, 0);
        }
    }
    __syncthreads();

    layer<4, false>(Wup, b_up, sA, sB, tid);
    __syncthreads();
    layer<8, true>(Wl1, b_l1, sB, sA, tid);
    __syncthreads();
    layer<8, true>(Wl2, b_l2, sA, sB, tid);
    __syncthreads();
    layer<8, true>(Wl3, b_l3, sB, sA, tid);
    __syncthreads();

    // out[n] = (x2[n,:] . W_out) * alpha[n]; 4 threads per node
    {
        int nl = tid >> 2, q = tid & 3;
        const ushort* rowp = sA + nl * PITCH + q * 64;
        float sum = 0.f;
#pragma unroll
        for (int o = 0; o < 64; ++o) {
            __hip_bfloat16 h = *(const __hip_bfloat16*)(rowp + o);
            sum = fmaf(__bfloat162float(h), W_out[q * 64 + o], sum);
        }
        sum += __shfl_xor(sum, 1);
        sum += __shfl_xor(sum, 2);
        int node = node0 + nl;
        if (q == 0 && node < N_CNT) out[node] = sum * alpha[node];
    }
}

__global__ __launch_bounds__(256) void batch_out_kernel(
    const int* __restrict__ batch, float* __restrict__ out)
{
    int n = blockIdx.x * 256 + threadIdx.x;
    if (n < N_CNT) out[N_CNT + n] = (float)batch[n];
}

extern "C" void kernel_launch(void* const* d_in, const int* in_sizes, int n_in,
                              void* d_out, int out_size, void* d_ws, size_t ws_size,
                              hipStream_t stream)
{
    const float* x      = (const float*)d_in[0];
    const float* rbf    = (const float*)d_in[1];
    const int*   nid    = (const int*)d_in[2];
    const int*   batch  = (const int*)d_in[5];
    const float* W_rbf  = (const float*)d_in[7];
    const float* W_up   = (const float*)d_in[8];
    const float* b_up   = (const float*)d_in[9];
    const float* W_l1   = (const float*)d_in[10];
    const float* b_l1   = (const float*)d_in[11];
    const float* W_l2   = (const float*)d_in[12];
    const float* b_l2   = (const float*)d_in[13];
    const float* W_l3   = (const float*)d_in[14];
    const float* b_l3   = (const float*)d_in[15];
    const float* W_out  = (const float*)d_in[16];
    const float* W_w    = (const float*)d_in[17];
    const float* b_w    = (const float*)d_in[18];

    char* ws = (char*)d_ws;
    int*    eids   = (int*)(ws + WS_EIDS);
    int*    offs   = (int*)(ws + WS_OFF);
    int*    cursor = (int*)(ws + WS_CURS);
    int*    counts = (int*)(ws + WS_CNT);
    float*  alpha  = (float*)(ws + WS_ALPHA);
    ushort* WupS   = (ushort*)(ws + WS_WUP);
    ushort* Wl1S   = (ushort*)(ws + WS_WL1);
    ushort* Wl2S   = (ushort*)(ws + WS_WL2);
    ushort* Wl3S   = (ushort*)(ws + WS_WL3);
    ushort* xn16   = (ushort*)(ws + WS_XN);
    float*  out    = (float*)d_out;

    hipMemsetAsync(counts, 0, N_CNT * sizeof(int), stream);
    hist_kernel<<<1024, 256, 0, stream>>>(nid, counts);
    scan_kernel<<<1, 1024, 0, stream>>>(counts, offs, cursor);
    fill_kernel<<<1024, 256, 0, stream>>>(nid, cursor, eids);

    wconv_kernel<<<(32768 + 255) / 256, 256, 0, stream>>>(W_up, WupS, H_DIM, 32768);
    wconv_kernel<<<256, 256, 0, stream>>>(W_l1, Wl1S, OE_DIM, 65536);
    wconv_kernel<<<256, 256, 0, stream>>>(W_l2, Wl2S, OE_DIM, 65536);
    wconv_kernel<<<256, 256, 0, stream>>>(W_l3, Wl3S, OE_DIM, 65536);

    gather_kernel<<<N_CNT / 4, 256, 0, stream>>>(x, rbf, offs, eids, W_rbf, W_w, b_w,
                                                 xn16, alpha);
    mlp_kernel<<<(N_CNT + MB - 1) / MB, 256, 0, stream>>>(
        xn16, WupS, Wl1S, Wl2S, Wl3S, b_up, b_l1, b_l2, b_l3, W_out, alpha, out);
    batch_out_kernel<<<(N_CNT + 255) / 256, 256, 0, stream>>>(batch, out);
}

// Round 3
// 251.220 us; speedup vs baseline: 7.9524x; 1.4942x over previous
//
#include <hip/hip_runtime.h>
#include <hip/hip_bf16.h>
#include <math.h>

#define E_CNT 600000
#define N_CNT 50000
#define H_DIM 128
#define OE_DIM 256

typedef __attribute__((ext_vector_type(8))) short short8;
typedef __attribute__((ext_vector_type(4))) float f32x4;

// ---------------- workspace layout (bytes), total ~16.8 MB
#define WS_EIDS   0            // int[E]            2,400,000
#define WS_OFF    2400000      // int[N+1]
#define WS_CURS   2600008      // int[N]
#define WS_CNT    2800008      // int[N]
#define WS_ALPHA  3000008      // float[N]
#define WS_WUP    3200016      // ushort[32768]
#define WS_WL1    3265552      // ushort[65536]
#define WS_WL2    3396624      // ushort[65536]
#define WS_WL3    3527696      // ushort[65536]
#define WS_TEXC   3700000      // int[50176]
#define WS_BSUM   3900704      // int[256]
#define WS_BEXC   3901728      // int[256]
#define WS_XN     4000000      // ushort[N*128]    12,800,000

#define SCAN_NB 196            // ceil(50000/256)

// ---------------------------------------------------------------------------
// CSR build: histogram -> coalesced two-level scan -> fill
// ---------------------------------------------------------------------------
__global__ __launch_bounds__(256) void hist_kernel(const int* __restrict__ nid,
                                                   int* __restrict__ counts)
{
    for (int e = blockIdx.x * 256 + threadIdx.x; e < E_CNT; e += gridDim.x * 256)
        atomicAdd(&counts[nid[e]], 1);
}

__global__ __launch_bounds__(256) void scanA_kernel(const int* __restrict__ counts,
                                                    int* __restrict__ texc,
                                                    int* __restrict__ bsum)
{
    __shared__ int s[256];
    const int t = threadIdx.x;
    const int i = blockIdx.x * 256 + t;
    int v = (i < N_CNT) ? counts[i] : 0;
    s[t] = v;
    __syncthreads();
    for (int off = 1; off < 256; off <<= 1) {
        int u = (t >= off) ? s[t - off] : 0;
        __syncthreads();
        s[t] += u;
        __syncthreads();
    }
    texc[i] = s[t] - v;                    // exclusive within tile
    if (t == 255) bsum[blockIdx.x] = s[255];
}

__global__ __launch_bounds__(256) void scanB_kernel(const int* __restrict__ bsum,
                                                    int* __restrict__ bexc)
{
    __shared__ int s[256];
    const int t = threadIdx.x;
    int v = (t < SCAN_NB) ? bsum[t] : 0;
    s[t] = v;
    __syncthreads();
    for (int off = 1; off < 256; off <<= 1) {
        int u = (t >= off) ? s[t - off] : 0;
        __syncthreads();
        s[t] += u;
        __syncthreads();
    }
    bexc[t] = s[t] - v;
}

__global__ __launch_bounds__(256) void scanC_kernel(const int* __restrict__ texc,
                                                    const int* __restrict__ bexc,
                                                    int* __restrict__ offs,
                                                    int* __restrict__ cursor)
{
    const int i = blockIdx.x * 256 + threadIdx.x;
    if (i < N_CNT) {
        int o = texc[i] + bexc[i >> 8];
        offs[i] = o;
        cursor[i] = o;
    }
    if (i == 0) offs[N_CNT] = E_CNT;
}

__global__ __launch_bounds__(256) void fill_kernel(const int* __restrict__ nid,
                                                   int* __restrict__ cursor,
                                                   int* __restrict__ eids)
{
    for (int e = blockIdx.x * 256 + threadIdx.x; e < E_CNT; e += gridDim.x * 256) {
        int slot = atomicAdd(&cursor[nid[e]], 1);
        eids[slot] = e;
    }
}

// ---------------------------------------------------------------------------
// Weight shuffle (all 4 matrices in one launch): f32 [O][K] -> bf16 MFMA
// b-frag order: dst[((ot*KS+ks)*64 + lane)*8 + j] = W[ot*16+(lane&15)][ks*32+8*(lane>>4)+j]
// ---------------------------------------------------------------------------
__global__ __launch_bounds__(256) void wconv_kernel(
    const float* __restrict__ Wup, const float* __restrict__ Wl1,
    const float* __restrict__ Wl2, const float* __restrict__ Wl3,
    ushort* __restrict__ dUp, ushort* __restrict__ dL1,
    ushort* __restrict__ dL2, ushort* __restrict__ dL3)
{
    int d = blockIdx.x * 256 + threadIdx.x;
    const float* W;
    ushort* dst;
    int K;
    if (d < 32768)       { W = Wup; dst = dUp; K = 128; }
    else if (d < 98304)  { d -= 32768;  W = Wl1; dst = dL1; K = 256; }
    else if (d < 163840) { d -= 98304;  W = Wl2; dst = dL2; K = 256; }
    else                 { d -= 163840; W = Wl3; dst = dL3; K = 256; }
    int j = d & 7;
    int l = (d >> 3) & 63;
    int KS = K >> 5;
    int ks = (d >> 9) % KS;
    int ot = (d >> 9) / KS;
    int k = ks * 32 + ((l >> 4) << 3) + j;
    int o = ot * 16 + (l & 15);
    __hip_bfloat16 h = __float2bfloat16(W[o * K + k]);
    dst[d] = *(const ushort*)&h;
}

// ---------------------------------------------------------------------------
// Gather: one wave per node. Lane&31 owns 4 h's (float4 loads, 16B/lane);
// lane>>5 picks which of an edge pair. Writes xn row as bf16 and alpha (f32).
// ---------------------------------------------------------------------------
__global__ __launch_bounds__(256) void gather_kernel(
    const float* __restrict__ x, const float* __restrict__ rbf,
    const int* __restrict__ offs, const int* __restrict__ eids,
    const float* __restrict__ W_rbf, const float* __restrict__ W_w,
    const float* __restrict__ b_w,
    ushort* __restrict__ xn16, float* __restrict__ alpha)
{
    const int lane = threadIdx.x & 63;
    const int node = blockIdx.x * 4 + (threadIdx.x >> 6);   // grid covers N exactly
    const int half = lane >> 5;
    const int hb = (lane & 31) * 4;

    float w[4][6];
#pragma unroll
    for (int j = 0; j < 4; ++j)
#pragma unroll
        for (int k = 0; k < 6; ++k)
            w[j][k] = W_rbf[(hb + j) * 6 + k];
    float ww[4];
#pragma unroll
    for (int j = 0; j < 4; ++j) ww[j] = W_w[hb + j];

    const int s = offs[node], e = offs[node + 1];
    float a0 = 0.f, a1 = 0.f, a2 = 0.f, a3 = 0.f;
    int i = s;
    for (; i + 1 < e; i += 2) {
        const int ee = eids[i + half];
        const float4 xv = *(const float4*)(x + (size_t)ee * H_DIM + hb);
        float r[6];
#pragma unroll
        for (int k = 0; k < 6; ++k) r[k] = rbf[ee * 6 + k];
        float c0 = 0.f, c1 = 0.f, c2 = 0.f, c3 = 0.f;
#pragma unroll
        for (int k = 0; k < 6; ++k) {
            c0 = fmaf(r[k], w[0][k], c0);
            c1 = fmaf(r[k], w[1][k], c1);
            c2 = fmaf(r[k], w[2][k], c2);
            c3 = fmaf(r[k], w[3][k], c3);
        }
        a0 = fmaf(c0, xv.x, a0);
        a1 = fmaf(c1, xv.y, a1);
        a2 = fmaf(c2, xv.z, a2);
        a3 = fmaf(c3, xv.w, a3);
    }
    if (i < e && half == 0) {               // odd leftover edge: lower half only
        const int ee = eids[i];
        const float4 xv = *(const float4*)(x + (size_t)ee * H_DIM + hb);
        float r[6];
#pragma unroll
        for (int k = 0; k < 6; ++k) r[k] = rbf[ee * 6 + k];
        float c0 = 0.f, c1 = 0.f, c2 = 0.f, c3 = 0.f;
#pragma unroll
        for (int k = 0; k < 6; ++k) {
            c0 = fmaf(r[k], w[0][k], c0);
            c1 = fmaf(r[k], w[1][k], c1);
            c2 = fmaf(r[k], w[2][k], c2);
            c3 = fmaf(r[k], w[3][k], c3);
        }
        a0 = fmaf(c0, xv.x, a0);
        a1 = fmaf(c1, xv.y, a1);
        a2 = fmaf(c2, xv.z, a2);
        a3 = fmaf(c3, xv.w, a3);
    }

    // combine edge-halves
    a0 += __shfl_xor(a0, 32);
    a1 += __shfl_xor(a1, 32);
    a2 += __shfl_xor(a2, 32);
    a3 += __shfl_xor(a3, 32);

    if (half == 0) {
        __hip_bfloat16 h0 = __float2bfloat16(a0), h1 = __float2bfloat16(a1);
        __hip_bfloat16 h2 = __float2bfloat16(a2), h3 = __float2bfloat16(a3);
        ushort4 pk;
        pk.x = *(const ushort*)&h0;
        pk.y = *(const ushort*)&h1;
        pk.z = *(const ushort*)&h2;
        pk.w = *(const ushort*)&h3;
        *(ushort4*)(xn16 + (size_t)node * H_DIM + hb) = pk;
    }

    float part = fmaf(a0, ww[0], fmaf(a1, ww[1], fmaf(a2, ww[2], a3 * ww[3])));
    part += __shfl_xor(part, 1);
    part += __shfl_xor(part, 2);
    part += __shfl_xor(part, 4);
    part += __shfl_xor(part, 8);
    part += __shfl_xor(part, 16);
    if (lane == 0) alpha[node] = part + b_w[0];
}

// ---------------------------------------------------------------------------
// MFMA MLP. 64 nodes/block, 512 threads (8 waves, 4 waves/SIMD at 2 blk/CU).
// Wave w owns o-tiles {2w, 2w+1}, all 4 m-tiles. Activations ping-pong in
// LDS (bf16, pitch 264 ush = 528 B -> 2-way banks = free).
// mfma_f32_16x16x32_bf16: a[lane l][j] = A[l&15][8*(l>>4)+j];
// D[lane l][r] = out[4*(l>>4)+r][l&15] (m89-verified mapping).
// ---------------------------------------------------------------------------
#define MB 64
#define PITCH 264

template<int KS, bool SW>
__device__ __forceinline__ void layer(const ushort* __restrict__ Wsh,
                                      const float* __restrict__ bias,
                                      const ushort* in_s, ushort* out_s, int tid)
{
    const int w = tid >> 6, lane = tid & 63;
    const int l15 = lane & 15, lg = lane >> 4;

    f32x4 acc[4][2];
#pragma unroll
    for (int mi = 0; mi < 4; ++mi)
#pragma unroll
        for (int oi = 0; oi < 2; ++oi)
            acc[mi][oi] = (f32x4){0.f, 0.f, 0.f, 0.f};

#pragma unroll
    for (int ks = 0; ks < KS; ++ks) {
        short8 b[2];
#pragma unroll
        for (int oi = 0; oi < 2; ++oi)
            b[oi] = *(const short8*)(Wsh + (size_t)(((w * 2 + oi) * KS + ks) * 64 + lane) * 8);
#pragma unroll
        for (int mi = 0; mi < 4; ++mi) {
            short8 a = *(const short8*)(in_s + (mi * 16 + l15) * PITCH + ks * 32 + lg * 8);
#pragma unroll
            for (int oi = 0; oi < 2; ++oi)
                acc[mi][oi] = __builtin_amdgcn_mfma_f32_16x16x32_bf16(a, b[oi], acc[mi][oi], 0, 0, 0);
        }
    }

#pragma unroll
    for (int oi = 0; oi < 2; ++oi) {
        float bv = bias[(w * 2 + oi) * 16 + l15];
#pragma unroll
        for (int mi = 0; mi < 4; ++mi)
#pragma unroll
            for (int r = 0; r < 4; ++r) {
                float v = acc[mi][oi][r] + bv;
                if (SW) v = v / (1.f + __expf(-v));
                __hip_bfloat16 h = __float2bfloat16(v);
                out_s[(mi * 16 + lg * 4 + r) * PITCH + (w * 2 + oi) * 16 + l15] =
                    *(const ushort*)&h;
            }
    }
}

__global__ __launch_bounds__(512, 4) void mlp_kernel(
    const ushort* __restrict__ xn16,
    const ushort* __restrict__ Wup, const ushort* __restrict__ Wl1,
    const ushort* __restrict__ Wl2, const ushort* __restrict__ Wl3,
    const float* __restrict__ b_up, const float* __restrict__ b_l1,
    const float* __restrict__ b_l2, const float* __restrict__ b_l3,
    const float* __restrict__ W_out, const float* __restrict__ alpha,
    const int* __restrict__ batch,
    float* __restrict__ out)
{
    __shared__ ushort sA[MB * PITCH];
    __shared__ ushort sB[MB * PITCH];
    const int tid = threadIdx.x;
    const int node0 = blockIdx.x * MB;

    // fold-in: batch -> out[N..2N)
    if (tid < MB) {
        int node = node0 + tid;
        if (node < N_CNT) out[N_CNT + node] = (float)batch[node];
    }

    // stage xn tile (bf16, 256 B/row): 8 threads/row, 2 int4 each
    {
        int row = tid >> 3, seg = tid & 7;
        int node = node0 + row;
        ushort* dst = sA + row * PITCH + seg * 16;
        if (node < N_CNT) {
            const int4* src = (const int4*)(xn16 + (size_t)node * H_DIM + seg * 16);
            *(int4*)(dst + 0) = src[0];
            *(int4*)(dst + 8) = src[1];
        } else {
            *(int4*)(dst + 0) = make_int4(0, 0, 0, 0);
            *(int4*)(dst + 8) = make_int4(0, 0, 0, 0);
        }
    }
    __syncthreads();

    layer<4, false>(Wup, b_up, sA, sB, tid);
    __syncthreads();
    layer<8, true>(Wl1, b_l1, sB, sA, tid);
    __syncthreads();
    layer<8, true>(Wl2, b_l2, sA, sB, tid);
    __syncthreads();
    layer<8, true>(Wl3, b_l3, sB, sA, tid);
    __syncthreads();

    // out[n] = (x2[n,:] . W_out) * alpha[n]; 8 threads per node, 32 o's each
    {
        int nl = tid >> 3, q = tid & 7;
        const ushort* rowp = sA + nl * PITCH + q * 32;
        float sum = 0.f;
#pragma unroll
        for (int o = 0; o < 32; ++o) {
            __hip_bfloat16 h = *(const __hip_bfloat16*)(rowp + o);
            sum = fmaf(__bfloat162float(h), W_out[q * 32 + o], sum);
        }
        sum += __shfl_xor(sum, 1);
        sum += __shfl_xor(sum, 2);
        sum += __shfl_xor(sum, 4);
        int node = node0 + nl;
        if (q == 0 && node < N_CNT) out[node] = sum * alpha[node];
    }
}

extern "C" void kernel_launch(void* const* d_in, const int* in_sizes, int n_in,
                              void* d_out, int out_size, void* d_ws, size_t ws_size,
                              hipStream_t stream)
{
    const float* x      = (const float*)d_in[0];
    const float* rbf    = (const float*)d_in[1];
    const int*   nid    = (const int*)d_in[2];
    const int*   batch  = (const int*)d_in[5];
    const float* W_rbf  = (const float*)d_in[7];
    const float* W_up   = (const float*)d_in[8];
    const float* b_up   = (const float*)d_in[9];
    const float* W_l1   = (const float*)d_in[10];
    const float* b_l1   = (const float*)d_in[11];
    const float* W_l2   = (const float*)d_in[12];
    const float* b_l2   = (const float*)d_in[13];
    const float* W_l3   = (const float*)d_in[14];
    const float* b_l3   = (const float*)d_in[15];
    const float* W_out  = (const float*)d_in[16];
    const float* W_w    = (const float*)d_in[17];
    const float* b_w    = (const float*)d_in[18];

    char* ws = (char*)d_ws;
    int*    eids   = (int*)(ws + WS_EIDS);
    int*    offs   = (int*)(ws + WS_OFF);
    int*    cursor = (int*)(ws + WS_CURS);
    int*    counts = (int*)(ws + WS_CNT);
    float*  alpha  = (float*)(ws + WS_ALPHA);
    ushort* WupS   = (ushort*)(ws + WS_WUP);
    ushort* Wl1S   = (ushort*)(ws + WS_WL1);
    ushort* Wl2S   = (ushort*)(ws + WS_WL2);
    ushort* Wl3S   = (ushort*)(ws + WS_WL3);
    int*    texc   = (int*)(ws + WS_TEXC);
    int*    bsum   = (int*)(ws + WS_BSUM);
    int*    bexc   = (int*)(ws + WS_BEXC);
    ushort* xn16   = (ushort*)(ws + WS_XN);
    float*  out    = (float*)d_out;

    hipMemsetAsync(counts, 0, N_CNT * sizeof(int), stream);
    hist_kernel<<<1024, 256, 0, stream>>>(nid, counts);
    scanA_kernel<<<SCAN_NB, 256, 0, stream>>>(counts, texc, bsum);
    scanB_kernel<<<1, 256, 0, stream>>>(bsum, bexc);
    scanC_kernel<<<SCAN_NB, 256, 0, stream>>>(texc, bexc, offs, cursor);
    fill_kernel<<<1024, 256, 0, stream>>>(nid, cursor, eids);

    wconv_kernel<<<896, 256, 0, stream>>>(W_up, W_l1, W_l2, W_l3,
                                          WupS, Wl1S, Wl2S, Wl3S);

    gather_kernel<<<N_CNT / 4, 256, 0, stream>>>(x, rbf, offs, eids, W_rbf, W_w, b_w,
                                                 xn16, alpha);
    mlp_kernel<<<(N_CNT + MB - 1) / MB, 512, 0, stream>>>(
        xn16, WupS, Wl1S, Wl2S, Wl3S, b_up, b_l1, b_l2, b_l3, W_out, alpha,
        batch, out);
}

// Round 4
// 226.689 us; speedup vs baseline: 8.8130x; 1.1082x over previous
//
#include <hip/hip_runtime.h>
#include <hip/hip_bf16.h>
#include <math.h>

#define E_CNT 600000
#define N_CNT 50000
#define H_DIM 128
#define OE_DIM 256

typedef __attribute__((ext_vector_type(8))) short short8;
typedef __attribute__((ext_vector_type(4))) float f32x4;

// ---------------- workspace layout (bytes), total ~4 MB
#define WS_EIDS   0            // int[E]            2,400,000
#define WS_OFF    2400000      // int[N+1]
#define WS_CURS   2600008      // int[N]
#define WS_CNT    2800008      // int[N]
#define WS_WUP    3000016      // ushort[32768]
#define WS_WL1    3065552      // ushort[65536]
#define WS_WL2    3196624      // ushort[65536]
#define WS_WL3    3327696      // ushort[65536]
#define WS_TEXC   3500000      // int[50176]
#define WS_BSUM   3700704      // int[256]
#define WS_BEXC   3701728      // int[256]

#define SCAN_NB 196            // ceil(50000/256)
#define WCONV_NB 896           // 229376/256

// ---------------------------------------------------------------------------
// Fused: weight shuffle (blocks 0..895) + histogram (blocks 896..1919).
// wconv: f32 [O][K] -> bf16 MFMA b-frag order:
//   dst[((ot*KS+ks)*64+lane)*8+j] = W[ot*16+(lane&15)][ks*32+8*(lane>>4)+j]
// ---------------------------------------------------------------------------
__global__ __launch_bounds__(256) void histwconv_kernel(
    const int* __restrict__ nid, int* __restrict__ counts,
    const float* __restrict__ Wup, const float* __restrict__ Wl1,
    const float* __restrict__ Wl2, const float* __restrict__ Wl3,
    ushort* __restrict__ dUp, ushort* __restrict__ dL1,
    ushort* __restrict__ dL2, ushort* __restrict__ dL3)
{
    if (blockIdx.x < WCONV_NB) {
        int d = blockIdx.x * 256 + threadIdx.x;
        const float* W;
        ushort* dst;
        int K;
        if (d < 32768)       { W = Wup; dst = dUp; K = 128; }
        else if (d < 98304)  { d -= 32768;  W = Wl1; dst = dL1; K = 256; }
        else if (d < 163840) { d -= 98304;  W = Wl2; dst = dL2; K = 256; }
        else                 { d -= 163840; W = Wl3; dst = dL3; K = 256; }
        int j = d & 7;
        int l = (d >> 3) & 63;
        int KS = K >> 5;
        int ks = (d >> 9) % KS;
        int ot = (d >> 9) / KS;
        int k = ks * 32 + ((l >> 4) << 3) + j;
        int o = ot * 16 + (l & 15);
        __hip_bfloat16 h = __float2bfloat16(W[o * K + k]);
        dst[d] = *(const ushort*)&h;
    } else {
        int nb = gridDim.x - WCONV_NB;
        for (int e = (blockIdx.x - WCONV_NB) * 256 + threadIdx.x; e < E_CNT;
             e += nb * 256)
            atomicAdd(&counts[nid[e]], 1);
    }
}

// ---------------------------------------------------------------------------
// Coalesced two-level scan + CSR fill
// ---------------------------------------------------------------------------
__global__ __launch_bounds__(256) void scanA_kernel(const int* __restrict__ counts,
                                                    int* __restrict__ texc,
                                                    int* __restrict__ bsum)
{
    __shared__ int s[256];
    const int t = threadIdx.x;
    const int i = blockIdx.x * 256 + t;
    int v = (i < N_CNT) ? counts[i] : 0;
    s[t] = v;
    __syncthreads();
    for (int off = 1; off < 256; off <<= 1) {
        int u = (t >= off) ? s[t - off] : 0;
        __syncthreads();
        s[t] += u;
        __syncthreads();
    }
    texc[i] = s[t] - v;
    if (t == 255) bsum[blockIdx.x] = s[255];
}

__global__ __launch_bounds__(256) void scanB_kernel(const int* __restrict__ bsum,
                                                    int* __restrict__ bexc)
{
    __shared__ int s[256];
    const int t = threadIdx.x;
    int v = (t < SCAN_NB) ? bsum[t] : 0;
    s[t] = v;
    __syncthreads();
    for (int off = 1; off < 256; off <<= 1) {
        int u = (t >= off) ? s[t - off] : 0;
        __syncthreads();
        s[t] += u;
        __syncthreads();
    }
    bexc[t] = s[t] - v;
}

__global__ __launch_bounds__(256) void scanC_kernel(const int* __restrict__ texc,
                                                    const int* __restrict__ bexc,
                                                    int* __restrict__ offs,
                                                    int* __restrict__ cursor)
{
    const int i = blockIdx.x * 256 + threadIdx.x;
    if (i < N_CNT) {
        int o = texc[i] + bexc[i >> 8];
        offs[i] = o;
        cursor[i] = o;
    }
    if (i == 0) offs[N_CNT] = E_CNT;
}

__global__ __launch_bounds__(256) void fill_kernel(const int* __restrict__ nid,
                                                   int* __restrict__ cursor,
                                                   int* __restrict__ eids)
{
    for (int e = blockIdx.x * 256 + threadIdx.x; e < E_CNT; e += gridDim.x * 256) {
        int slot = atomicAdd(&cursor[nid[e]], 1);
        eids[slot] = e;
    }
}

// ---------------------------------------------------------------------------
// Fused gather + MFMA MLP. 64 nodes/block, 512 threads (8 waves), 2 blk/CU.
// Phase 1: stage block's contiguous eids slice into LDS; wave w gathers
//   nodes 8w..8w+7 (lane&31 owns 4 h's via float4; lane>>5 picks edge of a
//   pair), writes bf16 rows directly into sA + alpha into LDS.
// Phase 2: 4-layer MFMA chain (ping-pong LDS, pitch 264 ush = 528 B) + dot.
// mfma_f32_16x16x32_bf16: a[lane l][j]=A[l&15][8*(l>>4)+j];
// D[lane l][r]=out[4*(l>>4)+r][l&15] (m89-verified).
// ---------------------------------------------------------------------------
#define MB 64
#define PITCH 264
#define EMAX 2048

template<int KS, bool SW>
__device__ __forceinline__ void layer(const ushort* __restrict__ Wsh,
                                      const float* __restrict__ bias,
                                      const ushort* in_s, ushort* out_s, int tid)
{
    const int w = tid >> 6, lane = tid & 63;
    const int l15 = lane & 15, lg = lane >> 4;

    f32x4 acc[4][2];
#pragma unroll
    for (int mi = 0; mi < 4; ++mi)
#pragma unroll
        for (int oi = 0; oi < 2; ++oi)
            acc[mi][oi] = (f32x4){0.f, 0.f, 0.f, 0.f};

#pragma unroll
    for (int ks = 0; ks < KS; ++ks) {
        short8 b[2];
#pragma unroll
        for (int oi = 0; oi < 2; ++oi)
            b[oi] = *(const short8*)(Wsh + (size_t)(((w * 2 + oi) * KS + ks) * 64 + lane) * 8);
#pragma unroll
        for (int mi = 0; mi < 4; ++mi) {
            short8 a = *(const short8*)(in_s + (mi * 16 + l15) * PITCH + ks * 32 + lg * 8);
#pragma unroll
            for (int oi = 0; oi < 2; ++oi)
                acc[mi][oi] = __builtin_amdgcn_mfma_f32_16x16x32_bf16(a, b[oi], acc[mi][oi], 0, 0, 0);
        }
    }

#pragma unroll
    for (int oi = 0; oi < 2; ++oi) {
        float bv = bias[(w * 2 + oi) * 16 + l15];
#pragma unroll
        for (int mi = 0; mi < 4; ++mi)
#pragma unroll
            for (int r = 0; r < 4; ++r) {
                float v = acc[mi][oi][r] + bv;
                if (SW) v = v / (1.f + __expf(-v));
                __hip_bfloat16 h = __float2bfloat16(v);
                out_s[(mi * 16 + lg * 4 + r) * PITCH + (w * 2 + oi) * 16 + l15] =
                    *(const ushort*)&h;
            }
    }
}

__global__ __launch_bounds__(512, 4) void fused_kernel(
    const float* __restrict__ x, const float* __restrict__ rbf,
    const int* __restrict__ offs, const int* __restrict__ eids,
    const float* __restrict__ W_rbf, const float* __restrict__ W_w,
    const float* __restrict__ b_w,
    const ushort* __restrict__ Wup, const ushort* __restrict__ Wl1,
    const ushort* __restrict__ Wl2, const ushort* __restrict__ Wl3,
    const float* __restrict__ b_up, const float* __restrict__ b_l1,
    const float* __restrict__ b_l2, const float* __restrict__ b_l3,
    const float* __restrict__ W_out, const int* __restrict__ batch,
    float* __restrict__ out)
{
    __shared__ ushort sA[MB * PITCH];
    __shared__ ushort sB[MB * PITCH];
    __shared__ float s_alpha[MB];
    __shared__ int s_eids[EMAX];

    const int tid = threadIdx.x;
    const int w = tid >> 6, lane = tid & 63;
    const int node0 = blockIdx.x * MB;

    // fold-in: batch -> out[N..2N)
    if (tid < MB) {
        int node = node0 + tid;
        if (node < N_CNT) out[N_CNT + node] = (float)batch[node];
    }

    // stage this block's contiguous eids slice
    const int nend = min(node0 + MB, N_CNT);
    const int s0 = offs[node0];
    const int tot = offs[nend] - s0;
    const bool staged = (tot <= EMAX);
    if (staged)
        for (int t = tid; t < tot; t += 512) s_eids[t] = eids[s0 + t];
    const int* ep = staged ? (const int*)s_eids : (eids + s0);
    __syncthreads();

    // ---- gather phase: wave w owns rows 8w..8w+7
    {
        const int half = lane >> 5;
        const int hb = (lane & 31) * 4;
        float wrb[4][6];
#pragma unroll
        for (int j = 0; j < 4; ++j)
#pragma unroll
            for (int k = 0; k < 6; ++k)
                wrb[j][k] = W_rbf[(hb + j) * 6 + k];
        float ww[4];
#pragma unroll
        for (int j = 0; j < 4; ++j) ww[j] = W_w[hb + j];

        for (int nl8 = 0; nl8 < 8; ++nl8) {
            const int nl = w * 8 + nl8;
            const int node = node0 + nl;
            int ls = 0, le = 0;
            if (node < N_CNT) {
                ls = offs[node] - s0;
                le = offs[node + 1] - s0;
            }
            float a0 = 0.f, a1 = 0.f, a2 = 0.f, a3 = 0.f;
            int i = ls;
            for (; i + 1 < le; i += 2) {
                const int ee = ep[i + half];
                const float4 xv = *(const float4*)(x + (size_t)ee * H_DIM + hb);
                float r[6];
#pragma unroll
                for (int k = 0; k < 6; ++k) r[k] = rbf[ee * 6 + k];
                float c0 = 0.f, c1 = 0.f, c2 = 0.f, c3 = 0.f;
#pragma unroll
                for (int k = 0; k < 6; ++k) {
                    c0 = fmaf(r[k], wrb[0][k], c0);
                    c1 = fmaf(r[k], wrb[1][k], c1);
                    c2 = fmaf(r[k], wrb[2][k], c2);
                    c3 = fmaf(r[k], wrb[3][k], c3);
                }
                a0 = fmaf(c0, xv.x, a0);
                a1 = fmaf(c1, xv.y, a1);
                a2 = fmaf(c2, xv.z, a2);
                a3 = fmaf(c3, xv.w, a3);
            }
            if (i < le && half == 0) {          // odd leftover edge
                const int ee = ep[i];
                const float4 xv = *(const float4*)(x + (size_t)ee * H_DIM + hb);
                float r[6];
#pragma unroll
                for (int k = 0; k < 6; ++k) r[k] = rbf[ee * 6 + k];
                float c0 = 0.f, c1 = 0.f, c2 = 0.f, c3 = 0.f;
#pragma unroll
                for (int k = 0; k < 6; ++k) {
                    c0 = fmaf(r[k], wrb[0][k], c0);
                    c1 = fmaf(r[k], wrb[1][k], c1);
                    c2 = fmaf(r[k], wrb[2][k], c2);
                    c3 = fmaf(r[k], wrb[3][k], c3);
                }
                a0 = fmaf(c0, xv.x, a0);
                a1 = fmaf(c1, xv.y, a1);
                a2 = fmaf(c2, xv.z, a2);
                a3 = fmaf(c3, xv.w, a3);
            }

            a0 += __shfl_xor(a0, 32);
            a1 += __shfl_xor(a1, 32);
            a2 += __shfl_xor(a2, 32);
            a3 += __shfl_xor(a3, 32);

            if (half == 0) {
                __hip_bfloat16 h0 = __float2bfloat16(a0), h1 = __float2bfloat16(a1);
                __hip_bfloat16 h2 = __float2bfloat16(a2), h3 = __float2bfloat16(a3);
                ushort4 pk;
                pk.x = *(const ushort*)&h0;
                pk.y = *(const ushort*)&h1;
                pk.z = *(const ushort*)&h2;
                pk.w = *(const ushort*)&h3;
                *(ushort4*)(sA + nl * PITCH + hb) = pk;
            }

            float part = fmaf(a0, ww[0], fmaf(a1, ww[1], fmaf(a2, ww[2], a3 * ww[3])));
            part += __shfl_xor(part, 1);
            part += __shfl_xor(part, 2);
            part += __shfl_xor(part, 4);
            part += __shfl_xor(part, 8);
            part += __shfl_xor(part, 16);
            if (lane == 0) s_alpha[nl] = part + b_w[0];
        }
    }
    __syncthreads();

    // ---- MLP phase
    layer<4, false>(Wup, b_up, sA, sB, tid);
    __syncthreads();
    layer<8, true>(Wl1, b_l1, sB, sA, tid);
    __syncthreads();
    layer<8, true>(Wl2, b_l2, sA, sB, tid);
    __syncthreads();
    layer<8, true>(Wl3, b_l3, sB, sA, tid);
    __syncthreads();

    // out[n] = (x2[n,:] . W_out) * alpha[n]; 8 threads per node
    {
        int nl = tid >> 3, q = tid & 7;
        const ushort* rowp = sA + nl * PITCH + q * 32;
        float sum = 0.f;
#pragma unroll
        for (int o = 0; o < 32; ++o) {
            __hip_bfloat16 h = *(const __hip_bfloat16*)(rowp + o);
            sum = fmaf(__bfloat162float(h), W_out[q * 32 + o], sum);
        }
        sum += __shfl_xor(sum, 1);
        sum += __shfl_xor(sum, 2);
        sum += __shfl_xor(sum, 4);
        int node = node0 + nl;
        if (q == 0 && node < N_CNT) out[node] = sum * s_alpha[nl];
    }
}

extern "C" void kernel_launch(void* const* d_in, const int* in_sizes, int n_in,
                              void* d_out, int out_size, void* d_ws, size_t ws_size,
                              hipStream_t stream)
{
    const float* x      = (const float*)d_in[0];
    const float* rbf    = (const float*)d_in[1];
    const int*   nid    = (const int*)d_in[2];
    const int*   batch  = (const int*)d_in[5];
    const float* W_rbf  = (const float*)d_in[7];
    const float* W_up   = (const float*)d_in[8];
    const float* b_up   = (const float*)d_in[9];
    const float* W_l1   = (const float*)d_in[10];
    const float* b_l1   = (const float*)d_in[11];
    const float* W_l2   = (const float*)d_in[12];
    const float* b_l2   = (const float*)d_in[13];
    const float* W_l3   = (const float*)d_in[14];
    const float* b_l3   = (const float*)d_in[15];
    const float* W_out  = (const float*)d_in[16];
    const float* W_w    = (const float*)d_in[17];
    const float* b_w    = (const float*)d_in[18];

    char* ws = (char*)d_ws;
    int*    eids   = (int*)(ws + WS_EIDS);
    int*    offs   = (int*)(ws + WS_OFF);
    int*    cursor = (int*)(ws + WS_CURS);
    int*    counts = (int*)(ws + WS_CNT);
    ushort* WupS   = (ushort*)(ws + WS_WUP);
    ushort* Wl1S   = (ushort*)(ws + WS_WL1);
    ushort* Wl2S   = (ushort*)(ws + WS_WL2);
    ushort* Wl3S   = (ushort*)(ws + WS_WL3);
    int*    texc   = (int*)(ws + WS_TEXC);
    int*    bsum   = (int*)(ws + WS_BSUM);
    int*    bexc   = (int*)(ws + WS_BEXC);
    float*  out    = (float*)d_out;

    hipMemsetAsync(counts, 0, N_CNT * sizeof(int), stream);
    histwconv_kernel<<<WCONV_NB + 1024, 256, 0, stream>>>(
        nid, counts, W_up, W_l1, W_l2, W_l3, WupS, Wl1S, Wl2S, Wl3S);
    scanA_kernel<<<SCAN_NB, 256, 0, stream>>>(counts, texc, bsum);
    scanB_kernel<<<1, 256, 0, stream>>>(bsum, bexc);
    scanC_kernel<<<SCAN_NB, 256, 0, stream>>>(texc, bexc, offs, cursor);
    fill_kernel<<<1024, 256, 0, stream>>>(nid, cursor, eids);

    fused_kernel<<<(N_CNT + MB - 1) / MB, 512, 0, stream>>>(
        x, rbf, offs, eids, W_rbf, W_w, b_w,
        WupS, Wl1S, Wl2S, Wl3S, b_up, b_l1, b_l2, b_l3, W_out, batch, out);
}